// Round 1
// baseline (619.647 us; speedup 1.0000x reference)
//
#include <hip/hip_runtime.h>
#include <math.h>

// Problem constants
#define S_DIM 128
#define Q_DIM 64
#define P_DIM 64
#define D_DIM 256
#define NQ (S_DIM * Q_DIM)   // 8192 question rows
#define NS (S_DIM * P_DIM)   // 8192 sentence rows
#define INV_TEMP (1.0f / 0.07f)

// ws layout (floats):
//  [0, 8192)        qinv
//  [8192, 16384)    sinv
//  [16384, 16512)   stinv
//  [16512, 24704)   total_exp   (zeroed)
//  [24704, 24832)   den         (zeroed)
//  [24832, 24960)   num         (zeroed)
//  [24960, 24962)   loss_acc (1 double, zeroed)

__global__ void init_kernel(float* __restrict__ p) {
    int i = blockIdx.x * 256 + threadIdx.x;
    if (i < 8450) p[i] = 0.0f;   // total_exp + den + num + loss_acc
}

// One wave per row: 64 lanes x float4 = 256 elems. 4 rows per block.
__global__ __launch_bounds__(256) void norms_kernel(
    const float* __restrict__ qm, const float* __restrict__ sm,
    const float* __restrict__ st,
    float* __restrict__ qinv, float* __restrict__ sinv, float* __restrict__ stinv) {
    int row = blockIdx.x * 4 + (threadIdx.x >> 6);
    int lane = threadIdx.x & 63;
    const float* src;
    float* dst;
    if (row < NQ)            { src = qm + (size_t)row * D_DIM;            dst = qinv + row; }
    else if (row < NQ + NS)  { src = sm + (size_t)(row - NQ) * D_DIM;     dst = sinv + (row - NQ); }
    else if (row < NQ + NS + S_DIM) { src = st + (size_t)(row - NQ - NS) * D_DIM; dst = stinv + (row - NQ - NS); }
    else return;
    float4 v = reinterpret_cast<const float4*>(src)[lane];
    float ss = v.x * v.x + v.y * v.y + v.z * v.z + v.w * v.w;
    #pragma unroll
    for (int off = 32; off; off >>= 1) ss += __shfl_xor(ss, off);
    if (lane == 0) *dst = 1.0f / fmaxf(sqrtf(ss), 1e-12f);
}

// Tiled A*B^T (both row-major, K=256) -> exp((dot*ainv*binv)/TEMP) -> row sums.
// BM=BN=128, BK=16, 256 threads, 8x8 micro-tile per thread.
// MASKED: also accumulate masked[row] over cols with (col>>6)==row (sq numerator).
template <bool MASKED>
__global__ __launch_bounds__(256) void simexp_kernel(
    const float* __restrict__ A, const float* __restrict__ B,
    const float* __restrict__ ainv, const float* __restrict__ binv,
    float* __restrict__ rowsum, float* __restrict__ masked) {
    __shared__ float As[16][128];  // transposed: As[k][row]
    __shared__ float Bs[16][128];
    const int tid = threadIdx.x;
    const int tx = tid & 15, ty = tid >> 4;
    const int row0 = blockIdx.y * 128, col0 = blockIdx.x * 128;

    float acc[8][8];
    #pragma unroll
    for (int i = 0; i < 8; i++)
        #pragma unroll
        for (int j = 0; j < 8; j++) acc[i][j] = 0.0f;

    for (int kc = 0; kc < D_DIM; kc += 16) {
        // Stage 128 rows x 16 k. f = i*256 + tid: r=f>>2, kq=(f&3)*4 (coalesced 64B/row).
        #pragma unroll
        for (int i = 0; i < 2; i++) {
            int f = i * 256 + tid;
            int r = f >> 2, kq = (f & 3) * 4;
            float4 va = *reinterpret_cast<const float4*>(&A[(size_t)(row0 + r) * D_DIM + kc + kq]);
            As[kq + 0][r] = va.x; As[kq + 1][r] = va.y; As[kq + 2][r] = va.z; As[kq + 3][r] = va.w;
            float4 vb = *reinterpret_cast<const float4*>(&B[(size_t)(col0 + r) * D_DIM + kc + kq]);
            Bs[kq + 0][r] = vb.x; Bs[kq + 1][r] = vb.y; Bs[kq + 2][r] = vb.z; Bs[kq + 3][r] = vb.w;
        }
        __syncthreads();
        #pragma unroll
        for (int k = 0; k < 16; k++) {
            float a[8], b[8];
            *reinterpret_cast<float4*>(a)     = *reinterpret_cast<float4*>(&As[k][ty * 8]);
            *reinterpret_cast<float4*>(a + 4) = *reinterpret_cast<float4*>(&As[k][ty * 8 + 4]);
            *reinterpret_cast<float4*>(b)     = *reinterpret_cast<float4*>(&Bs[k][tx * 8]);
            *reinterpret_cast<float4*>(b + 4) = *reinterpret_cast<float4*>(&Bs[k][tx * 8 + 4]);
            #pragma unroll
            for (int i = 0; i < 8; i++)
                #pragma unroll
                for (int j = 0; j < 8; j++)
                    acc[i][j] = fmaf(a[i], b[j], acc[i][j]);
        }
        __syncthreads();
    }

    float ai[8], bi[8];
    #pragma unroll
    for (int i = 0; i < 8; i++) ai[i] = ainv[row0 + ty * 8 + i];
    #pragma unroll
    for (int j = 0; j < 8; j++) bi[j] = binv[col0 + tx * 8 + j];

    #pragma unroll
    for (int i = 0; i < 8; i++) {
        const int grow = row0 + ty * 8 + i;
        float rs = 0.0f, nm = 0.0f;
        #pragma unroll
        for (int j = 0; j < 8; j++) {
            float e = expf(acc[i][j] * (ai[i] * bi[j] * INV_TEMP));
            rs += e;
            if (MASKED) {
                int col = col0 + tx * 8 + j;
                if ((col >> 6) == grow) nm += e;
            }
        }
        // reduce across tx (lanes differing in low 4 bits)
        #pragma unroll
        for (int off = 1; off < 16; off <<= 1) {
            rs += __shfl_xor(rs, off);
            if (MASKED) nm += __shfl_xor(nm, off);
        }
        if (tx == 0) {
            atomicAdd(&rowsum[grow], rs);
            if (MASKED) atomicAdd(&masked[grow], nm);
        }
    }
}

// qs_loss: block handles (section s, 32 questions). Recomputes own-section dots.
__global__ __launch_bounds__(256) void qs_loss_kernel(
    const float* __restrict__ Qm, const float* __restrict__ Sm,
    const float* __restrict__ qinv, const float* __restrict__ sinv,
    const float* __restrict__ total_exp, double* __restrict__ loss_acc) {
    const int s = blockIdx.x >> 1;
    const int q0 = (blockIdx.x & 1) * 32;
    const int tid = threadIdx.x;
    const int p = tid >> 2;    // 0..63
    const int dq = tid & 3;    // d-quarter
    __shared__ float pos_s[64];
    __shared__ double wsum[4];
    const float term2 = expf((float)(-1.0 / 0.07)) * (float)(NS - 1);

    const float* srow = Sm + ((size_t)(s * P_DIM + p)) * D_DIM + dq * 64;
    const float sinv_p = sinv[s * P_DIM + p];
    double lacc = 0.0;

    for (int qq = 0; qq < 32; qq++) {
        const int row = s * Q_DIM + q0 + qq;
        const float* qrow = Qm + (size_t)row * D_DIM + dq * 64;
        float dot = 0.0f;
        #pragma unroll
        for (int d4 = 0; d4 < 16; d4++) {
            float4 a = reinterpret_cast<const float4*>(qrow)[d4];
            float4 b = reinterpret_cast<const float4*>(srow)[d4];
            dot = fmaf(a.x, b.x, fmaf(a.y, b.y, fmaf(a.z, b.z, fmaf(a.w, b.w, dot))));
        }
        dot += __shfl_xor(dot, 1);
        dot += __shfl_xor(dot, 2);   // all 4 dq lanes now hold full dot
        float pos = expf(dot * (qinv[row] * sinv_p * INV_TEMP));
        if (dq == 0) pos_s[p] = pos;
        __syncthreads();
        float pv = pos_s[tid & 63];
        float oe = pv;
        #pragma unroll
        for (int off = 1; off < 64; off <<= 1) oe += __shfl_xor(oe, off);  // own_exp
        float neg = total_exp[row] - oe;
        if (tid < 64) {
            float posv = pos_s[tid];
            float t1 = fmaf(-0.1f, posv, neg / (1.0f - 0.1f));
            float Ng = fmaxf(fmaxf(t1, term2), 1e-8f);
            lacc += (double)(-logf(posv / (posv + Ng)));
        }
        __syncthreads();
    }
    #pragma unroll
    for (int off = 1; off < 64; off <<= 1) lacc += __shfl_xor(lacc, off);
    if ((tid & 63) == 0) wsum[tid >> 6] = lacc;
    __syncthreads();
    if (tid == 0) atomicAdd(loss_acc, wsum[0] + wsum[1] + wsum[2] + wsum[3]);
}

__global__ __launch_bounds__(128) void finalize_kernel(
    const float* __restrict__ den, const float* __restrict__ num,
    const double* __restrict__ loss_acc, float* __restrict__ out) {
    const int tid = threadIdx.x;  // 128 threads, one per section
    __shared__ float w2[2];
    float l = -logf(num[tid] / den[tid]);
    #pragma unroll
    for (int off = 1; off < 64; off <<= 1) l += __shfl_xor(l, off);
    if ((tid & 63) == 0) w2[tid >> 6] = l;
    __syncthreads();
    if (tid == 0) out[0] = (float)(loss_acc[0] + (double)(w2[0] + w2[1]));
    // at_loss = -log(x/x) = 0 exactly; omitted.
}

extern "C" void kernel_launch(void* const* d_in, const int* in_sizes, int n_in,
                              void* d_out, int out_size, void* d_ws, size_t ws_size,
                              hipStream_t stream) {
    const float* st = (const float*)d_in[1];   // [128,256] section titles
    const float* qm = (const float*)d_in[2];   // [128,64,256] questions
    const float* sm = (const float*)d_in[3];   // [128,64,256] sentences

    float* ws        = (float*)d_ws;
    float* qinv      = ws;
    float* sinv      = ws + 8192;
    float* stinv     = ws + 16384;
    float* total_exp = ws + 16512;
    float* den       = ws + 24704;
    float* num       = ws + 24832;
    double* loss_acc = (double*)(ws + 24960);
    float* out       = (float*)d_out;

    hipLaunchKernelGGL(init_kernel, dim3(34), dim3(256), 0, stream, total_exp);
    hipLaunchKernelGGL(norms_kernel, dim3(4128), dim3(256), 0, stream,
                       qm, sm, st, qinv, sinv, stinv);
    // Phase A: total_exp[row] = sum_m exp(sim/TEMP) over all 8192 sentences
    hipLaunchKernelGGL((simexp_kernel<false>), dim3(64, 64), dim3(256), 0, stream,
                       qm, sm, qinv, sinv, total_exp, (float*)nullptr);
    // Phase B: qs_loss
    hipLaunchKernelGGL(qs_loss_kernel, dim3(256), dim3(256), 0, stream,
                       qm, sm, qinv, sinv, total_exp, loss_acc);
    // Phase C: sq_loss denominator/numerator (A=section titles, B=questions)
    hipLaunchKernelGGL((simexp_kernel<true>), dim3(64, 1), dim3(256), 0, stream,
                       st, qm, stinv, qinv, den, num);
    hipLaunchKernelGGL(finalize_kernel, dim3(1), dim3(128), 0, stream,
                       den, num, loss_acc, out);
}

// Round 2
// 355.824 us; speedup vs baseline: 1.7414x; 1.7414x over previous
//
#include <hip/hip_runtime.h>
#include <math.h>

// Problem constants
#define S_DIM 128
#define Q_DIM 64
#define P_DIM 64
#define D_DIM 256
#define NQ (S_DIM * Q_DIM)   // 8192 question rows
#define NS (S_DIM * P_DIM)   // 8192 sentence rows
#define INV_TEMP (1.0f / 0.07f)

typedef __attribute__((ext_vector_type(4))) float f32x4;
typedef __attribute__((ext_vector_type(8))) short bf16x8;

// ---------- helpers ----------
__device__ __forceinline__ unsigned short f2bf(float f) {
    unsigned int u = __float_as_uint(f);
    u = (u + 0x7fffu + ((u >> 16) & 1u)) >> 16;   // RNE (no NaN inputs here)
    return (unsigned short)u;
}
__device__ __forceinline__ float bf2f(unsigned short h) {
    return __uint_as_float(((unsigned int)h) << 16);
}
__device__ __forceinline__ void gload_lds16(const void* g, void* l) {
    __builtin_amdgcn_global_load_lds(
        (const __attribute__((address_space(1))) void*)g,
        (__attribute__((address_space(3))) void*)l, 16, 0, 0);
}

// ws layout (float units):
//  [0, 8192)        qinv
//  [8192, 16384)    sinv
//  [16384, 16512)   stinv
//  [16512, 24704)   total_exp   (zeroed)
//  [24704, 24832)   den         (zeroed)
//  [24832, 24960)   num         (zeroed)
//  [24960, 24962)   loss_acc (1 double, zeroed)
//  [25088, ...)     bf16 region: q_hi, q_lo, s_hi, s_lo, st_hi, st_lo
//  total ~17.1 MB of ws needed.

__global__ void init_kernel(float* __restrict__ p) {
    int i = blockIdx.x * 256 + threadIdx.x;
    if (i < 8450) p[i] = 0.0f;   // total_exp + den + num + loss_acc
}

// One wave per row: compute inv-norm, write inv, and write scaled bf16 hi/lo split.
// Scale folded per-row: inv_norm * sqrt(INV_TEMP * log2(e)) so that
// exp(sim/TEMP) == exp2(dot(hi+lo scaled)).
__global__ __launch_bounds__(256) void normsplit_kernel(
    const float* __restrict__ qm, const float* __restrict__ sm,
    const float* __restrict__ st,
    float* __restrict__ qinv, float* __restrict__ sinv, float* __restrict__ stinv,
    unsigned short* __restrict__ q_hi, unsigned short* __restrict__ q_lo,
    unsigned short* __restrict__ s_hi, unsigned short* __restrict__ s_lo,
    unsigned short* __restrict__ st_hi, unsigned short* __restrict__ st_lo) {
    int row = blockIdx.x * 4 + (threadIdx.x >> 6);
    int lane = threadIdx.x & 63;
    const float* src;
    float* inv_dst;
    unsigned short *hi, *lo;
    int r;
    if (row < NQ) {
        r = row; src = qm + (size_t)r * D_DIM; inv_dst = qinv + r;
        hi = q_hi + (size_t)r * D_DIM; lo = q_lo + (size_t)r * D_DIM;
    } else if (row < NQ + NS) {
        r = row - NQ; src = sm + (size_t)r * D_DIM; inv_dst = sinv + r;
        hi = s_hi + (size_t)r * D_DIM; lo = s_lo + (size_t)r * D_DIM;
    } else if (row < NQ + NS + S_DIM) {
        r = row - NQ - NS; src = st + (size_t)r * D_DIM; inv_dst = stinv + r;
        hi = st_hi + (size_t)r * D_DIM; lo = st_lo + (size_t)r * D_DIM;
    } else return;

    float4 v = reinterpret_cast<const float4*>(src)[lane];
    float ss = v.x * v.x + v.y * v.y + v.z * v.z + v.w * v.w;
    #pragma unroll
    for (int off = 32; off; off >>= 1) ss += __shfl_xor(ss, off);
    float inv = 1.0f / fmaxf(sqrtf(ss), 1e-12f);
    if (lane == 0) *inv_dst = inv;

    const float CF = sqrtf((1.0f / 0.07f) * 1.44269504088896f);  // folded: compiler-const
    float sc = inv * CF;
    float x[4] = {v.x * sc, v.y * sc, v.z * sc, v.w * sc};
    ushort4 h, l;
    unsigned short* hp = &h.x; unsigned short* lp = &l.x;
    #pragma unroll
    for (int e = 0; e < 4; e++) {
        unsigned short hh = f2bf(x[e]);
        hp[e] = hh;
        lp[e] = f2bf(x[e] - bf2f(hh));
    }
    reinterpret_cast<ushort4*>(hi)[lane] = h;
    reinterpret_cast<ushort4*>(lo)[lane] = l;
}

// bf16x3-split MFMA GEMM (A*B^T, rows pre-scaled) with fused exp2 + row-sum.
// BM=BN=128, BK=32, 256 threads (4 waves, 2x2), wave tile 64x64 (4x4 frags of 16x16x32).
// Effective K = 3 passes x 256: hi*hi + hi*lo + lo*hi.
// MASKED: also accumulate masked[row] over cols with (col>>6)==row (sq numerator).
template <bool MASKED>
__global__ __launch_bounds__(256) void mfma_simexp_kernel(
    const unsigned short* __restrict__ Ahi, const unsigned short* __restrict__ Alo,
    const unsigned short* __restrict__ Bhi, const unsigned short* __restrict__ Blo,
    float* __restrict__ rowsum, float* __restrict__ masked) {
    __shared__ unsigned short sA[128 * 32];   // 8 KB, row-major [128 rows][32 k]
    __shared__ unsigned short sB[128 * 32];   // 8 KB
    const int tid = threadIdx.x;
    const int wid = tid >> 6, lane = tid & 63;
    const int wr = wid >> 1, wc = wid & 1;          // wave tile position (2x2)
    const int row0 = blockIdx.y * 128, col0 = blockIdx.x * 128;

    f32x4 acc[4][4];
    #pragma unroll
    for (int m = 0; m < 4; m++)
        #pragma unroll
        for (int n = 0; n < 4; n++) acc[m][n] = (f32x4){0.f, 0.f, 0.f, 0.f};

    const unsigned short* Apass[3] = {Ahi, Ahi, Alo};
    const unsigned short* Bpass[3] = {Bhi, Blo, Bhi};

    // staging geometry: per tile 8192 B; wave w covers bytes [w*2048, w*2048+2048)
    // via 2 chunks of 1024 B (64 lanes x 16 B). LDS byte o -> row=o/64, kbyte=o%64.
    const int o_base = wid * 2048 + lane * 16;

    for (int pass = 0; pass < 3; pass++) {
        const unsigned short* Asrc = Apass[pass];
        const unsigned short* Bsrc = Bpass[pass];
        for (int kc = 0; kc < D_DIM; kc += 32) {
            #pragma unroll
            for (int i = 0; i < 2; i++) {
                int o = o_base + i * 1024;
                int r = o >> 6, kk = (o & 63) >> 1;
                gload_lds16(Asrc + (((size_t)(row0 + r)) << 8) + kc + kk,
                            (char*)sA + wid * 2048 + i * 1024);
                gload_lds16(Bsrc + (((size_t)(col0 + r)) << 8) + kc + kk,
                            (char*)sB + wid * 2048 + i * 1024);
            }
            __syncthreads();
            bf16x8 a[4], b[4];
            #pragma unroll
            for (int m = 0; m < 4; m++)
                a[m] = *reinterpret_cast<const bf16x8*>(
                    &sA[(wr * 64 + m * 16 + (lane & 15)) * 32 + (lane >> 4) * 8]);
            #pragma unroll
            for (int n = 0; n < 4; n++)
                b[n] = *reinterpret_cast<const bf16x8*>(
                    &sB[(wc * 64 + n * 16 + (lane & 15)) * 32 + (lane >> 4) * 8]);
            #pragma unroll
            for (int m = 0; m < 4; m++)
                #pragma unroll
                for (int n = 0; n < 4; n++)
                    acc[m][n] = __builtin_amdgcn_mfma_f32_16x16x32_bf16(
                        a[m], b[n], acc[m][n], 0, 0, 0);
            __syncthreads();
        }
    }

    // Epilogue: e = exp2(acc); row-sum over this block's 128 cols; atomic add.
    // C/D layout (16x16): col = lane&15, row = (lane>>4)*4 + reg.
    #pragma unroll
    for (int m = 0; m < 4; m++) {
        #pragma unroll
        for (int j = 0; j < 4; j++) {
            const int grow = row0 + wr * 64 + m * 16 + (lane >> 4) * 4 + j;
            float rs = 0.0f, nm = 0.0f;
            #pragma unroll
            for (int n = 0; n < 4; n++) {
                float e = exp2f(acc[m][n][j]);
                rs += e;
                if (MASKED) {
                    int col = col0 + wc * 64 + n * 16 + (lane & 15);
                    if ((col >> 6) == grow) nm += e;
                }
            }
            #pragma unroll
            for (int off = 1; off < 16; off <<= 1) {
                rs += __shfl_xor(rs, off);
                if (MASKED) nm += __shfl_xor(nm, off);
            }
            if ((lane & 15) == 0) {
                atomicAdd(&rowsum[grow], rs);
                if (MASKED) atomicAdd(&masked[grow], nm);
            }
        }
    }
}

// qs_loss: block handles (section s, 32 questions). Recomputes own-section dots in fp32.
__global__ __launch_bounds__(256) void qs_loss_kernel(
    const float* __restrict__ Qm, const float* __restrict__ Sm,
    const float* __restrict__ qinv, const float* __restrict__ sinv,
    const float* __restrict__ total_exp, double* __restrict__ loss_acc) {
    const int s = blockIdx.x >> 1;
    const int q0 = (blockIdx.x & 1) * 32;
    const int tid = threadIdx.x;
    const int p = tid >> 2;    // 0..63
    const int dq = tid & 3;    // d-quarter
    __shared__ float pos_s[64];
    __shared__ double wsum[4];
    const float term2 = expf((float)(-1.0 / 0.07)) * (float)(NS - 1);

    const float* srow = Sm + ((size_t)(s * P_DIM + p)) * D_DIM + dq * 64;
    const float sinv_p = sinv[s * P_DIM + p];
    double lacc = 0.0;

    for (int qq = 0; qq < 32; qq++) {
        const int row = s * Q_DIM + q0 + qq;
        const float* qrow = Qm + (size_t)row * D_DIM + dq * 64;
        float dot = 0.0f;
        #pragma unroll
        for (int d4 = 0; d4 < 16; d4++) {
            float4 a = reinterpret_cast<const float4*>(qrow)[d4];
            float4 b = reinterpret_cast<const float4*>(srow)[d4];
            dot = fmaf(a.x, b.x, fmaf(a.y, b.y, fmaf(a.z, b.z, fmaf(a.w, b.w, dot))));
        }
        dot += __shfl_xor(dot, 1);
        dot += __shfl_xor(dot, 2);   // all 4 dq lanes now hold full dot
        float pos = expf(dot * (qinv[row] * sinv_p * INV_TEMP));
        if (dq == 0) pos_s[p] = pos;
        __syncthreads();
        float pv = pos_s[tid & 63];
        float oe = pv;
        #pragma unroll
        for (int off = 1; off < 64; off <<= 1) oe += __shfl_xor(oe, off);  // own_exp
        float neg = total_exp[row] - oe;
        if (tid < 64) {
            float posv = pos_s[tid];
            float t1 = fmaf(-0.1f, posv, neg / (1.0f - 0.1f));
            float Ng = fmaxf(fmaxf(t1, term2), 1e-8f);
            lacc += (double)(-logf(posv / (posv + Ng)));
        }
        __syncthreads();
    }
    #pragma unroll
    for (int off = 1; off < 64; off <<= 1) lacc += __shfl_xor(lacc, off);
    if ((tid & 63) == 0) wsum[tid >> 6] = lacc;
    __syncthreads();
    if (tid == 0) atomicAdd(loss_acc, wsum[0] + wsum[1] + wsum[2] + wsum[3]);
}

__global__ __launch_bounds__(128) void finalize_kernel(
    const float* __restrict__ den, const float* __restrict__ num,
    const double* __restrict__ loss_acc, float* __restrict__ out) {
    const int tid = threadIdx.x;  // 128 threads, one per section
    __shared__ float w2[2];
    float l = -logf(num[tid] / den[tid]);
    #pragma unroll
    for (int off = 1; off < 64; off <<= 1) l += __shfl_xor(l, off);
    if ((tid & 63) == 0) w2[tid >> 6] = l;
    __syncthreads();
    if (tid == 0) out[0] = (float)(loss_acc[0] + (double)(w2[0] + w2[1]));
    // at_loss = -log(x/x) = 0 exactly; omitted.
}

extern "C" void kernel_launch(void* const* d_in, const int* in_sizes, int n_in,
                              void* d_out, int out_size, void* d_ws, size_t ws_size,
                              hipStream_t stream) {
    const float* st = (const float*)d_in[1];   // [128,256] section titles
    const float* qm = (const float*)d_in[2];   // [128,64,256] questions
    const float* sm = (const float*)d_in[3];   // [128,64,256] sentences

    float* ws        = (float*)d_ws;
    float* qinv      = ws;
    float* sinv      = ws + 8192;
    float* stinv     = ws + 16384;
    float* total_exp = ws + 16512;
    float* den       = ws + 24704;
    float* num       = ws + 24832;
    double* loss_acc = (double*)(ws + 24960);
    unsigned short* b16 = (unsigned short*)(ws + 25088);
    unsigned short* q_hi  = b16;
    unsigned short* q_lo  = b16 + 2097152;
    unsigned short* s_hi  = b16 + 4194304;
    unsigned short* s_lo  = b16 + 6291456;
    unsigned short* st_hi = b16 + 8388608;
    unsigned short* st_lo = b16 + 8421376;
    float* out = (float*)d_out;

    hipLaunchKernelGGL(init_kernel, dim3(34), dim3(256), 0, stream, total_exp);
    hipLaunchKernelGGL(normsplit_kernel, dim3(4128), dim3(256), 0, stream,
                       qm, sm, st, qinv, sinv, stinv,
                       q_hi, q_lo, s_hi, s_lo, st_hi, st_lo);
    // Phase A: total_exp[q-row] = sum over all 8192 sentences of exp(sim/TEMP)
    hipLaunchKernelGGL((mfma_simexp_kernel<false>), dim3(64, 64), dim3(256), 0, stream,
                       q_hi, q_lo, s_hi, s_lo, total_exp, (float*)nullptr);
    // Phase B: qs_loss
    hipLaunchKernelGGL(qs_loss_kernel, dim3(256), dim3(256), 0, stream,
                       qm, sm, qinv, sinv, total_exp, loss_acc);
    // Phase C: sq_loss denominator (all sections) + numerator (own-section mask)
    hipLaunchKernelGGL((mfma_simexp_kernel<true>), dim3(64, 1), dim3(256), 0, stream,
                       st_hi, st_lo, q_hi, q_lo, den, num);
    hipLaunchKernelGGL(finalize_kernel, dim3(1), dim3(128), 0, stream,
                       den, num, loss_acc, out);
}

// Round 3
// 260.145 us; speedup vs baseline: 2.3819x; 1.3678x over previous
//
#include <hip/hip_runtime.h>
#include <math.h>

// Problem constants
#define S_DIM 128
#define Q_DIM 64
#define P_DIM 64
#define D_DIM 256
#define NQ (S_DIM * Q_DIM)   // 8192 question rows
#define NS (S_DIM * P_DIM)   // 8192 sentence rows

typedef __attribute__((ext_vector_type(4))) float f32x4;
typedef __attribute__((ext_vector_type(8))) short bf16x8;

// ---------- helpers ----------
__device__ __forceinline__ unsigned short f2bf(float f) {
    unsigned int u = __float_as_uint(f);
    u = (u + 0x7fffu + ((u >> 16) & 1u)) >> 16;   // RNE (no NaN inputs here)
    return (unsigned short)u;
}
__device__ __forceinline__ float bf2f(unsigned short h) {
    return __uint_as_float(((unsigned int)h) << 16);
}
__device__ __forceinline__ void gload_lds16(const void* g, void* l) {
    __builtin_amdgcn_global_load_lds(
        (const __attribute__((address_space(1))) void*)g,
        (__attribute__((address_space(3))) void*)l, 16, 0, 0);
}

// ws layout (float units):
//  [0, 8192)      total_exp (zeroed)
//  [8192, 8320)   den       (zeroed)
//  [8320, 8448)   num       (zeroed)
//  [8448, 8450)   loss_acc (1 double, zeroed)
//  [8704, ...)    bf16: q_hi(2M) q_lo(2M) s_hi(2M) s_lo(2M) st_hi(32K) st_lo(32K)
//  total ~17.0 MB.

__global__ void init_kernel(float* __restrict__ p) {
    int i = blockIdx.x * 256 + threadIdx.x;
    if (i < 8450) p[i] = 0.0f;
}

// One wave per row: inv-norm + scaled bf16 hi/lo split.
// Scale folded per-row: inv_norm * sqrt((1/TEMP)*log2(e)) so that
// exp(sim/TEMP) == exp2(dot(hi+lo scaled)).
__global__ __launch_bounds__(256) void normsplit_kernel(
    const float* __restrict__ qm, const float* __restrict__ sm,
    const float* __restrict__ st,
    unsigned short* __restrict__ q_hi, unsigned short* __restrict__ q_lo,
    unsigned short* __restrict__ s_hi, unsigned short* __restrict__ s_lo,
    unsigned short* __restrict__ st_hi, unsigned short* __restrict__ st_lo) {
    int row = blockIdx.x * 4 + (threadIdx.x >> 6);
    int lane = threadIdx.x & 63;
    const float* src;
    unsigned short *hi, *lo;
    int r;
    if (row < NQ) {
        r = row; src = qm + (size_t)r * D_DIM;
        hi = q_hi + (size_t)r * D_DIM; lo = q_lo + (size_t)r * D_DIM;
    } else if (row < NQ + NS) {
        r = row - NQ; src = sm + (size_t)r * D_DIM;
        hi = s_hi + (size_t)r * D_DIM; lo = s_lo + (size_t)r * D_DIM;
    } else if (row < NQ + NS + S_DIM) {
        r = row - NQ - NS; src = st + (size_t)r * D_DIM;
        hi = st_hi + (size_t)r * D_DIM; lo = st_lo + (size_t)r * D_DIM;
    } else return;

    float4 v = reinterpret_cast<const float4*>(src)[lane];
    float ss = v.x * v.x + v.y * v.y + v.z * v.z + v.w * v.w;
    #pragma unroll
    for (int off = 32; off; off >>= 1) ss += __shfl_xor(ss, off);
    float inv = 1.0f / fmaxf(sqrtf(ss), 1e-12f);

    const float CF = sqrtf((1.0f / 0.07f) * 1.44269504088896f);
    float sc = inv * CF;
    float x[4] = {v.x * sc, v.y * sc, v.z * sc, v.w * sc};
    ushort4 h, l;
    unsigned short* hp = &h.x; unsigned short* lp = &l.x;
    #pragma unroll
    for (int e = 0; e < 4; e++) {
        unsigned short hh = f2bf(x[e]);
        hp[e] = hh;
        lp[e] = f2bf(x[e] - bf2f(hh));
    }
    reinterpret_cast<ushort4*>(hi)[lane] = h;
    reinterpret_cast<ushort4*>(lo)[lane] = l;
}

// Fused bf16x3-split MFMA GEMM (A*B^T, rows pre-scaled) with exp2 + row-sum.
// BM=BN=128, BK=32, 256 threads (4 waves, 2x2), wave tile 64x64.
// All 3 products (hi*hi + hi*lo + lo*hi) inside one k-loop: 4 tiles staged per
// chunk, 48 MFMA per wave per chunk, double-buffered LDS (64 KB), one barrier
// per chunk (T3 minimum 2-phase).
// MASKED: also accumulate masked[row] over cols with (col>>6)==row (sq numerator).
template <bool MASKED>
__global__ __launch_bounds__(256, 2) void mfma_simexp_kernel(
    const unsigned short* __restrict__ Ahi, const unsigned short* __restrict__ Alo,
    const unsigned short* __restrict__ Bhi, const unsigned short* __restrict__ Blo,
    float* __restrict__ rowsum, float* __restrict__ masked) {
    __shared__ unsigned short lds[2][4][128 * 32];   // [buf][Ah,Al,Bh,Bl] = 64 KB
    const int tid = threadIdx.x;
    const int wid = tid >> 6, lane = tid & 63;
    const int wr = wid >> 1, wc = wid & 1;
    const int row0 = blockIdx.y * 128, col0 = blockIdx.x * 128;

    f32x4 acc[4][4];
    #pragma unroll
    for (int m = 0; m < 4; m++)
        #pragma unroll
        for (int n = 0; n < 4; n++) acc[m][n] = (f32x4){0.f, 0.f, 0.f, 0.f};

    // Stage all 4 tiles for k-chunk kc into lds[buf]. LDS dest is wave-uniform
    // base + lane*16 (HW); per-lane source offset computed from o.
    auto STAGE = [&](int buf, int kc) {
        #pragma unroll
        for (int i = 0; i < 2; i++) {
            const int doff = wid * 2048 + i * 1024;       // byte offset in tile
            const int o = doff + lane * 16;
            const int r = o >> 6;                          // tile row
            const int kk = (o & 63) >> 1;                  // elem offset in row
            const size_t ga = ((size_t)(row0 + r) << 8) + kc + kk;
            const size_t gb = ((size_t)(col0 + r) << 8) + kc + kk;
            gload_lds16(Ahi + ga, (char*)&lds[buf][0][0] + doff);
            gload_lds16(Alo + ga, (char*)&lds[buf][1][0] + doff);
            gload_lds16(Bhi + gb, (char*)&lds[buf][2][0] + doff);
            gload_lds16(Blo + gb, (char*)&lds[buf][3][0] + doff);
        }
    };

    STAGE(0, 0);
    __syncthreads();   // drains vmcnt(0) per-wave before barrier -> buf0 ready
    int cur = 0;
    for (int t = 0; t < 8; t++) {
        if (t < 7) STAGE(cur ^ 1, (t + 1) * 32);
        const unsigned short* Ah = lds[cur][0];
        const unsigned short* Al = lds[cur][1];
        const unsigned short* Bh = lds[cur][2];
        const unsigned short* Bl = lds[cur][3];
        bf16x8 ah[4], al[4], bh[4], bl[4];
        #pragma unroll
        for (int m = 0; m < 4; m++) {
            const int off = (wr * 64 + m * 16 + (lane & 15)) * 32 + (lane >> 4) * 8;
            ah[m] = *reinterpret_cast<const bf16x8*>(&Ah[off]);
            al[m] = *reinterpret_cast<const bf16x8*>(&Al[off]);
        }
        #pragma unroll
        for (int n = 0; n < 4; n++) {
            const int off = (wc * 64 + n * 16 + (lane & 15)) * 32 + (lane >> 4) * 8;
            bh[n] = *reinterpret_cast<const bf16x8*>(&Bh[off]);
            bl[n] = *reinterpret_cast<const bf16x8*>(&Bl[off]);
        }
        #pragma unroll
        for (int m = 0; m < 4; m++)
            #pragma unroll
            for (int n = 0; n < 4; n++) {
                acc[m][n] = __builtin_amdgcn_mfma_f32_16x16x32_bf16(ah[m], bh[n], acc[m][n], 0, 0, 0);
                acc[m][n] = __builtin_amdgcn_mfma_f32_16x16x32_bf16(ah[m], bl[n], acc[m][n], 0, 0, 0);
                acc[m][n] = __builtin_amdgcn_mfma_f32_16x16x32_bf16(al[m], bh[n], acc[m][n], 0, 0, 0);
            }
        __syncthreads();   // drains the prefetch + guards buf reuse
        cur ^= 1;
    }

    // Epilogue: e = exp2(acc); row-sum over this block's 128 cols; atomic add.
    // C/D layout (16x16): col = lane&15, row = (lane>>4)*4 + reg.
    #pragma unroll
    for (int m = 0; m < 4; m++) {
        #pragma unroll
        for (int j = 0; j < 4; j++) {
            const int grow = row0 + wr * 64 + m * 16 + (lane >> 4) * 4 + j;
            float rs = 0.0f, nm = 0.0f;
            #pragma unroll
            for (int n = 0; n < 4; n++) {
                float e = exp2f(acc[m][n][j]);
                rs += e;
                if (MASKED) {
                    int col = col0 + wc * 64 + n * 16 + (lane & 15);
                    if ((col >> 6) == grow) nm += e;
                }
            }
            #pragma unroll
            for (int off = 1; off < 16; off <<= 1) {
                rs += __shfl_xor(rs, off);
                if (MASKED) nm += __shfl_xor(nm, off);
            }
            if ((lane & 15) == 0) {
                atomicAdd(&rowsum[grow], rs);
                if (MASKED) atomicAdd(&masked[grow], nm);
            }
        }
    }
}

// qs_loss: one block per section (128 blocks). Recomputes own-section pos via
// bf16x3 MFMA with fragments loaded straight from L2 (no LDS, no k-barriers),
// then emits loss terms: -log(pos/(pos+Ng)).
__global__ __launch_bounds__(256) void qs2_kernel(
    const unsigned short* __restrict__ q_hi, const unsigned short* __restrict__ q_lo,
    const unsigned short* __restrict__ s_hi, const unsigned short* __restrict__ s_lo,
    const float* __restrict__ total_exp, double* __restrict__ loss_acc) {
    const int s = blockIdx.x;
    const int tid = threadIdx.x;
    const int wid = tid >> 6, lane = tid & 63;
    __shared__ double wsum[4];

    // wave wid computes q-rows [s*64 + wid*16, +16) x all 64 sentences.
    f32x4 acc[4];
    #pragma unroll
    for (int n = 0; n < 4; n++) acc[n] = (f32x4){0.f, 0.f, 0.f, 0.f};

    const int arow = s * 64 + wid * 16 + (lane & 15);
    const int koff = (lane >> 4) * 8;
    for (int kc = 0; kc < D_DIM; kc += 32) {
        bf16x8 ah = *reinterpret_cast<const bf16x8*>(&q_hi[(size_t)arow * D_DIM + kc + koff]);
        bf16x8 al = *reinterpret_cast<const bf16x8*>(&q_lo[(size_t)arow * D_DIM + kc + koff]);
        #pragma unroll
        for (int n = 0; n < 4; n++) {
            const int brow = s * 64 + n * 16 + (lane & 15);
            bf16x8 bh = *reinterpret_cast<const bf16x8*>(&s_hi[(size_t)brow * D_DIM + kc + koff]);
            bf16x8 bl = *reinterpret_cast<const bf16x8*>(&s_lo[(size_t)brow * D_DIM + kc + koff]);
            acc[n] = __builtin_amdgcn_mfma_f32_16x16x32_bf16(ah, bh, acc[n], 0, 0, 0);
            acc[n] = __builtin_amdgcn_mfma_f32_16x16x32_bf16(ah, bl, acc[n], 0, 0, 0);
            acc[n] = __builtin_amdgcn_mfma_f32_16x16x32_bf16(al, bh, acc[n], 0, 0, 0);
        }
    }

    const float term2 = expf(-1.0f / 0.07f) * (float)(NS - 1);
    double lacc = 0.0;
    #pragma unroll
    for (int j = 0; j < 4; j++) {
        // pos for q-row (C-layout row) = s*64 + wid*16 + (lane>>4)*4 + j
        float own = acc[0][j] >= 0.f ? 0.f : 0.f;  // placeholder, computed below
        float e[4];
        float part = 0.0f;
        #pragma unroll
        for (int n = 0; n < 4; n++) { e[n] = exp2f(acc[n][j]); part += e[n]; }
        #pragma unroll
        for (int off = 1; off < 16; off <<= 1) part += __shfl_xor(part, off);
        own = part;  // own_exp, broadcast to all 16 lanes of the group
        const int trow = s * 64 + wid * 16 + (lane >> 4) * 4 + j;
        const float neg = total_exp[trow] - own;
        #pragma unroll
        for (int n = 0; n < 4; n++) {
            float posv = e[n];
            float t1 = fmaf(-0.1f, posv, neg / 0.9f);
            float Ng = fmaxf(fmaxf(t1, term2), 1e-8f);
            lacc += (double)(-logf(posv / (posv + Ng)));
        }
    }
    #pragma unroll
    for (int off = 1; off < 64; off <<= 1) lacc += __shfl_xor(lacc, off);
    if (lane == 0) wsum[wid] = lacc;
    __syncthreads();
    if (tid == 0) atomicAdd(loss_acc, wsum[0] + wsum[1] + wsum[2] + wsum[3]);
}

__global__ __launch_bounds__(128) void finalize_kernel(
    const float* __restrict__ den, const float* __restrict__ num,
    const double* __restrict__ loss_acc, float* __restrict__ out) {
    const int tid = threadIdx.x;  // 128 threads, one per section
    __shared__ float w2[2];
    float l = -logf(num[tid] / den[tid]);
    #pragma unroll
    for (int off = 1; off < 64; off <<= 1) l += __shfl_xor(l, off);
    if ((tid & 63) == 0) w2[tid >> 6] = l;
    __syncthreads();
    if (tid == 0) out[0] = (float)(loss_acc[0] + (double)(w2[0] + w2[1]));
    // at_loss = -log(x/x) = 0 exactly; omitted.
}

extern "C" void kernel_launch(void* const* d_in, const int* in_sizes, int n_in,
                              void* d_out, int out_size, void* d_ws, size_t ws_size,
                              hipStream_t stream) {
    const float* st = (const float*)d_in[1];   // [128,256]
    const float* qm = (const float*)d_in[2];   // [128,64,256]
    const float* sm = (const float*)d_in[3];   // [128,64,256]

    float* ws        = (float*)d_ws;
    float* total_exp = ws;
    float* den       = ws + 8192;
    float* num       = ws + 8320;
    double* loss_acc = (double*)(ws + 8448);
    unsigned short* b16 = (unsigned short*)(ws + 8704);
    unsigned short* q_hi  = b16;
    unsigned short* q_lo  = b16 + 2097152;
    unsigned short* s_hi  = b16 + 4194304;
    unsigned short* s_lo  = b16 + 6291456;
    unsigned short* st_hi = b16 + 8388608;
    unsigned short* st_lo = b16 + 8421376;
    float* out = (float*)d_out;

    hipLaunchKernelGGL(init_kernel, dim3(34), dim3(256), 0, stream, ws);
    hipLaunchKernelGGL(normsplit_kernel, dim3(4224), dim3(256), 0, stream,
                       qm, sm, st, q_hi, q_lo, s_hi, s_lo, st_hi, st_lo);
    // Phase A: total_exp[q-row] = sum over all 8192 sentences of exp(sim/TEMP)
    hipLaunchKernelGGL((mfma_simexp_kernel<false>), dim3(64, 64), dim3(256), 0, stream,
                       q_hi, q_lo, s_hi, s_lo, total_exp, (float*)nullptr);
    // Phase C: sq_loss denominator (all sections) + numerator (own-section mask)
    hipLaunchKernelGGL((mfma_simexp_kernel<true>), dim3(64, 1), dim3(256), 0, stream,
                       st_hi, st_lo, q_hi, q_lo, den, num);
    // Phase B: qs_loss from recomputed own-section pos + total_exp
    hipLaunchKernelGGL(qs2_kernel, dim3(128), dim3(256), 0, stream,
                       q_hi, q_lo, s_hi, s_lo, total_exp, loss_acc);
    hipLaunchKernelGGL(finalize_kernel, dim3(1), dim3(128), 0, stream,
                       den, num, loss_acc, out);
}

// Round 4
// 254.926 us; speedup vs baseline: 2.4307x; 1.0205x over previous
//
#include <hip/hip_runtime.h>
#include <math.h>

// Problem constants
#define S_DIM 128
#define Q_DIM 64
#define P_DIM 64
#define D_DIM 256
#define NQ (S_DIM * Q_DIM)   // 8192 question rows
#define NS (S_DIM * P_DIM)   // 8192 sentence rows

typedef __attribute__((ext_vector_type(4))) float f32x4;
typedef __attribute__((ext_vector_type(8))) short bf16x8;

// ---------- helpers ----------
__device__ __forceinline__ unsigned short f2bf(float f) {
    unsigned int u = __float_as_uint(f);
    u = (u + 0x7fffu + ((u >> 16) & 1u)) >> 16;   // RNE (no NaN inputs here)
    return (unsigned short)u;
}
__device__ __forceinline__ float bf2f(unsigned short h) {
    return __uint_as_float(((unsigned int)h) << 16);
}
__device__ __forceinline__ void gload_lds16(const void* g, void* l) {
    __builtin_amdgcn_global_load_lds(
        (const __attribute__((address_space(1))) void*)g,
        (__attribute__((address_space(3))) void*)l, 16, 0, 0);
}

// ws layout (float units):
//  [0, 8192)      total_exp (zeroed)
//  [8192, 8320)   den       (zeroed)
//  [8320, 8448)   num       (zeroed)
//  [8448, 8450)   loss_acc (1 double, zeroed)
//  [8452]         ticket    (zeroed)
//  [8704, ...)    bf16: q_hi(2M) q_lo(2M) s_hi(2M) s_lo(2M) st_hi(32K) st_lo(32K)

// One wave per row: inv-norm + scaled bf16 hi/lo split. Blocks 0..33 also zero
// the accumulator region (consumed only by later kernels in stream order).
// Scale folded per-row: inv_norm * sqrt((1/TEMP)*log2(e)) so that
// exp(sim/TEMP) == exp2(dot(hi+lo scaled)).
__global__ __launch_bounds__(256) void normsplit_kernel(
    const float* __restrict__ qm, const float* __restrict__ sm,
    const float* __restrict__ st, float* __restrict__ zero_region,
    unsigned short* __restrict__ q_hi, unsigned short* __restrict__ q_lo,
    unsigned short* __restrict__ s_hi, unsigned short* __restrict__ s_lo,
    unsigned short* __restrict__ st_hi, unsigned short* __restrict__ st_lo) {
    if (blockIdx.x < 34) {
        int i = blockIdx.x * 256 + threadIdx.x;
        if (i < 8456) zero_region[i] = 0.0f;
    }
    int row = blockIdx.x * 4 + (threadIdx.x >> 6);
    int lane = threadIdx.x & 63;
    const float* src;
    unsigned short *hi, *lo;
    int r;
    if (row < NQ) {
        r = row; src = qm + (size_t)r * D_DIM;
        hi = q_hi + (size_t)r * D_DIM; lo = q_lo + (size_t)r * D_DIM;
    } else if (row < NQ + NS) {
        r = row - NQ; src = sm + (size_t)r * D_DIM;
        hi = s_hi + (size_t)r * D_DIM; lo = s_lo + (size_t)r * D_DIM;
    } else if (row < NQ + NS + S_DIM) {
        r = row - NQ - NS; src = st + (size_t)r * D_DIM;
        hi = st_hi + (size_t)r * D_DIM; lo = st_lo + (size_t)r * D_DIM;
    } else return;

    float4 v = reinterpret_cast<const float4*>(src)[lane];
    float ss = v.x * v.x + v.y * v.y + v.z * v.z + v.w * v.w;
    #pragma unroll
    for (int off = 32; off; off >>= 1) ss += __shfl_xor(ss, off);
    float inv = 1.0f / fmaxf(sqrtf(ss), 1e-12f);

    const float CF = sqrtf((1.0f / 0.07f) * 1.44269504088896f);
    float sc = inv * CF;
    float x[4] = {v.x * sc, v.y * sc, v.z * sc, v.w * sc};
    ushort4 h, l;
    unsigned short* hp = &h.x; unsigned short* lp = &l.x;
    #pragma unroll
    for (int e = 0; e < 4; e++) {
        unsigned short hh = f2bf(x[e]);
        hp[e] = hh;
        lp[e] = f2bf(x[e] - bf2f(hh));
    }
    reinterpret_cast<ushort4*>(hi)[lane] = h;
    reinterpret_cast<ushort4*>(lo)[lane] = l;
}

// Fused bf16x3-split MFMA GEMM (A*B^T, rows pre-scaled) + exp2 + row-sum.
// BM=BN=128, BK=32, 4 waves (2x2), wave tile 64x64, double-buffered LDS (64KB).
// LDS tile layout is pair-interleaved XOR-swizzled for conflict-free b128 reads:
//   element (r, kg=k>>3) lives at byte pair*128 + ((((r&1)<<2)+kg) ^ (pair&7))*16,
//   pair = r>>1. global_load_lds writes LINEAR dest; the per-lane global SOURCE
//   address is the inverse mapping (rule #21 / m173 pattern).
// Grid (64, 65): y<64  -> A-pass: total_exp[q-row] += sum exp over s-cols
//                y==64 -> C-pass: den[st-row] += sum exp over q-cols, plus
//                         masked own-section numerator num[st-row].
__global__ __launch_bounds__(256, 2) void mfma_simexp_kernel(
    const unsigned short* __restrict__ q_hi, const unsigned short* __restrict__ q_lo,
    const unsigned short* __restrict__ s_hi, const unsigned short* __restrict__ s_lo,
    const unsigned short* __restrict__ st_hi, const unsigned short* __restrict__ st_lo,
    float* __restrict__ total_exp, float* __restrict__ den, float* __restrict__ num) {
    __shared__ unsigned short lds[2][4][4096];   // [buf][Ah,Al,Bh,Bl] = 64 KB
    const bool cpass = (blockIdx.y == 64);
    const unsigned short* Ahi = cpass ? st_hi : q_hi;
    const unsigned short* Alo = cpass ? st_lo : q_lo;
    const unsigned short* Bhi = cpass ? q_hi : s_hi;
    const unsigned short* Blo = cpass ? q_lo : s_lo;
    float* rowsum = cpass ? den : total_exp;

    const int tid = threadIdx.x;
    const int wid = tid >> 6, lane = tid & 63;
    const int wr = wid >> 1, wc = wid & 1;
    const int row0 = cpass ? 0 : blockIdx.y * 128;
    const int col0 = blockIdx.x * 128;

    f32x4 acc[4][4];
    #pragma unroll
    for (int m = 0; m < 4; m++)
        #pragma unroll
        for (int n = 0; n < 4; n++) acc[m][n] = (f32x4){0.f, 0.f, 0.f, 0.f};

    // Stage all 4 tensors for k-chunk kc into lds[buf]: linear LDS dest,
    // swizzle-decoded per-lane global source.
    auto STAGE = [&](int buf, int kc) {
        #pragma unroll
        for (int i = 0; i < 2; i++) {
            const int doff = wid * 2048 + i * 1024;       // wave-uniform dest byte
            const int o = doff + lane * 16;               // this lane's dest byte
            const int pair = o >> 7;
            const int slot = ((o >> 4) & 7) ^ (pair & 7); // inverse swizzle
            const int r = pair * 2 + (slot >> 2);
            const int kk = (slot & 3) * 8;
            const size_t ga = ((size_t)(row0 + r) << 8) + kc + kk;
            const size_t gb = ((size_t)(col0 + r) << 8) + kc + kk;
            gload_lds16(Ahi + ga, (char*)&lds[buf][0][0] + doff);
            gload_lds16(Alo + ga, (char*)&lds[buf][1][0] + doff);
            gload_lds16(Bhi + gb, (char*)&lds[buf][2][0] + doff);
            gload_lds16(Blo + gb, (char*)&lds[buf][3][0] + doff);
        }
    };
    // swizzled read offset for element row R, k-group kg (this lane's frag slice)
    const int kg = lane >> 4;
    auto OFF = [&](int R) {
        int pair = R >> 1;
        int slot = ((R & 1) << 2) + kg;
        return pair * 128 + ((slot ^ (pair & 7)) << 4);
    };

    STAGE(0, 0);
    __syncthreads();
    int cur = 0;
    for (int t = 0; t < 8; t++) {
        if (t < 7) STAGE(cur ^ 1, (t + 1) * 32);
        const char* Ah = (const char*)&lds[cur][0][0];
        const char* Al = (const char*)&lds[cur][1][0];
        const char* Bh = (const char*)&lds[cur][2][0];
        const char* Bl = (const char*)&lds[cur][3][0];
        bf16x8 ah[4], al[4], bh[4], bl[4];
        #pragma unroll
        for (int m = 0; m < 4; m++) {
            const int off = OFF(wr * 64 + m * 16 + (lane & 15));
            ah[m] = *reinterpret_cast<const bf16x8*>(Ah + off);
            al[m] = *reinterpret_cast<const bf16x8*>(Al + off);
        }
        #pragma unroll
        for (int n = 0; n < 4; n++) {
            const int off = OFF(wc * 64 + n * 16 + (lane & 15));
            bh[n] = *reinterpret_cast<const bf16x8*>(Bh + off);
            bl[n] = *reinterpret_cast<const bf16x8*>(Bl + off);
        }
        #pragma unroll
        for (int m = 0; m < 4; m++)
            #pragma unroll
            for (int n = 0; n < 4; n++) {
                acc[m][n] = __builtin_amdgcn_mfma_f32_16x16x32_bf16(ah[m], bh[n], acc[m][n], 0, 0, 0);
                acc[m][n] = __builtin_amdgcn_mfma_f32_16x16x32_bf16(ah[m], bl[n], acc[m][n], 0, 0, 0);
                acc[m][n] = __builtin_amdgcn_mfma_f32_16x16x32_bf16(al[m], bh[n], acc[m][n], 0, 0, 0);
            }
        __syncthreads();   // drains prefetch (vmcnt 0) + guards buf reuse
        cur ^= 1;
    }

    // Epilogue: e = exp2(acc); row-sum over this block's 128 cols; atomic add.
    // C/D layout (16x16): col = lane&15, row = (lane>>4)*4 + reg.
    #pragma unroll
    for (int m = 0; m < 4; m++) {
        #pragma unroll
        for (int j = 0; j < 4; j++) {
            const int grow = row0 + wr * 64 + m * 16 + (lane >> 4) * 4 + j;
            float rs = 0.0f, nm = 0.0f;
            #pragma unroll
            for (int n = 0; n < 4; n++) {
                float e = exp2f(acc[m][n][j]);
                rs += e;
                if (cpass) {
                    int col = col0 + wc * 64 + n * 16 + (lane & 15);
                    if ((col >> 6) == grow) nm += e;
                }
            }
            #pragma unroll
            for (int off = 1; off < 16; off <<= 1) {
                rs += __shfl_xor(rs, off);
                if (cpass) nm += __shfl_xor(nm, off);
            }
            if ((lane & 15) == 0) {
                atomicAdd(&rowsum[grow], rs);
                if (cpass) atomicAdd(&num[grow], nm);
            }
        }
    }
}

// qs_loss + finalize. 256 blocks x 128 threads (2 waves); block handles half a
// section (2 wave-tiles of 16 q-rows x 64 sentences). Recomputes own-section
// pos via bf16x3 MFMA straight from L2. Last block (ticket) finalizes.
__global__ __launch_bounds__(128) void qs2_kernel(
    const unsigned short* __restrict__ q_hi, const unsigned short* __restrict__ q_lo,
    const unsigned short* __restrict__ s_hi, const unsigned short* __restrict__ s_lo,
    const float* __restrict__ total_exp, const float* __restrict__ den,
    const float* __restrict__ num, double* __restrict__ loss_acc,
    unsigned int* __restrict__ ticket, float* __restrict__ out) {
    const int s = blockIdx.x >> 1;
    const int tid = threadIdx.x;
    const int wid2 = ((blockIdx.x & 1) << 1) + (tid >> 6);   // 0..3 within section
    const int lane = tid & 63;
    __shared__ double wsum[2];
    __shared__ float w2[2];
    __shared__ unsigned int winner_s;

    f32x4 acc[4];
    #pragma unroll
    for (int n = 0; n < 4; n++) acc[n] = (f32x4){0.f, 0.f, 0.f, 0.f};

    const int arow = s * 64 + wid2 * 16 + (lane & 15);
    const int koff = (lane >> 4) * 8;
    for (int kc = 0; kc < D_DIM; kc += 32) {
        bf16x8 ah = *reinterpret_cast<const bf16x8*>(&q_hi[(size_t)arow * D_DIM + kc + koff]);
        bf16x8 al = *reinterpret_cast<const bf16x8*>(&q_lo[(size_t)arow * D_DIM + kc + koff]);
        #pragma unroll
        for (int n = 0; n < 4; n++) {
            const int brow = s * 64 + n * 16 + (lane & 15);
            bf16x8 bh = *reinterpret_cast<const bf16x8*>(&s_hi[(size_t)brow * D_DIM + kc + koff]);
            bf16x8 bl = *reinterpret_cast<const bf16x8*>(&s_lo[(size_t)brow * D_DIM + kc + koff]);
            acc[n] = __builtin_amdgcn_mfma_f32_16x16x32_bf16(ah, bh, acc[n], 0, 0, 0);
            acc[n] = __builtin_amdgcn_mfma_f32_16x16x32_bf16(ah, bl, acc[n], 0, 0, 0);
            acc[n] = __builtin_amdgcn_mfma_f32_16x16x32_bf16(al, bh, acc[n], 0, 0, 0);
        }
    }

    const float term2 = expf(-1.0f / 0.07f) * (float)(NS - 1);
    double lacc = 0.0;
    #pragma unroll
    for (int j = 0; j < 4; j++) {
        float e[4];
        float part = 0.0f;
        #pragma unroll
        for (int n = 0; n < 4; n++) { e[n] = exp2f(acc[n][j]); part += e[n]; }
        #pragma unroll
        for (int off = 1; off < 16; off <<= 1) part += __shfl_xor(part, off);
        const int trow = s * 64 + wid2 * 16 + (lane >> 4) * 4 + j;
        const float neg = total_exp[trow] - part;
        #pragma unroll
        for (int n = 0; n < 4; n++) {
            float posv = e[n];
            float t1 = fmaf(-0.1f, posv, neg / 0.9f);
            float Ng = fmaxf(fmaxf(t1, term2), 1e-8f);
            lacc += (double)(-logf(posv / (posv + Ng)));
        }
    }
    #pragma unroll
    for (int off = 1; off < 64; off <<= 1) lacc += __shfl_xor(lacc, off);
    if (lane == 0) wsum[tid >> 6] = lacc;
    __syncthreads();
    if (tid == 0) {
        atomicAdd(loss_acc, wsum[0] + wsum[1]);
        __threadfence();
        winner_s = atomicAdd(ticket, 1u);
    }
    __syncthreads();
    if (winner_s == 255) {
        __threadfence();   // acquire: all other blocks' loss atomics visible
        float l = -logf(num[tid] / den[tid]);   // tid = 0..127 = section
        #pragma unroll
        for (int off = 1; off < 64; off <<= 1) l += __shfl_xor(l, off);
        if ((tid & 63) == 0) w2[tid >> 6] = l;
        __syncthreads();
        if (tid == 0) out[0] = (float)(loss_acc[0] + (double)(w2[0] + w2[1]));
        // at_loss = -log(x/x) = 0 exactly; omitted.
    }
}

extern "C" void kernel_launch(void* const* d_in, const int* in_sizes, int n_in,
                              void* d_out, int out_size, void* d_ws, size_t ws_size,
                              hipStream_t stream) {
    const float* st = (const float*)d_in[1];   // [128,256]
    const float* qm = (const float*)d_in[2];   // [128,64,256]
    const float* sm = (const float*)d_in[3];   // [128,64,256]

    float* ws        = (float*)d_ws;
    float* total_exp = ws;
    float* den       = ws + 8192;
    float* num       = ws + 8320;
    double* loss_acc = (double*)(ws + 8448);
    unsigned int* ticket = (unsigned int*)(ws + 8452);
    unsigned short* b16 = (unsigned short*)(ws + 8704);
    unsigned short* q_hi  = b16;
    unsigned short* q_lo  = b16 + 2097152;
    unsigned short* s_hi  = b16 + 4194304;
    unsigned short* s_lo  = b16 + 6291456;
    unsigned short* st_hi = b16 + 8388608;
    unsigned short* st_lo = b16 + 8421376;
    float* out = (float*)d_out;

    // 1: zero accumulators + norm + bf16 hi/lo split
    hipLaunchKernelGGL(normsplit_kernel, dim3(4224), dim3(256), 0, stream,
                       qm, sm, st, ws, q_hi, q_lo, s_hi, s_lo, st_hi, st_lo);
    // 2: phase A (y<64): total_exp; phase C (y==64): den/num
    hipLaunchKernelGGL(mfma_simexp_kernel, dim3(64, 65), dim3(256), 0, stream,
                       q_hi, q_lo, s_hi, s_lo, st_hi, st_lo, total_exp, den, num);
    // 3: qs_loss + finalize (ticketed last block)
    hipLaunchKernelGGL(qs2_kernel, dim3(256), dim3(128), 0, stream,
                       q_hi, q_lo, s_hi, s_lo, total_exp, den, num,
                       loss_acc, ticket, out);
}

// Round 5
// 207.277 us; speedup vs baseline: 2.9895x; 1.2299x over previous
//
#include <hip/hip_runtime.h>
#include <math.h>

// Problem constants
#define S_DIM 128
#define Q_DIM 64
#define P_DIM 64
#define D_DIM 256
#define NQ (S_DIM * Q_DIM)   // 8192 question rows
#define NS (S_DIM * P_DIM)   // 8192 sentence rows

typedef __attribute__((ext_vector_type(4))) float f32x4;
typedef __attribute__((ext_vector_type(8))) short bf16x8;
typedef __attribute__((ext_vector_type(8))) _Float16 f16x8;
typedef __attribute__((ext_vector_type(4))) _Float16 f16x4;

// ---------- helpers ----------
__device__ __forceinline__ unsigned short f2bf(float f) {
    unsigned int u = __float_as_uint(f);
    u = (u + 0x7fffu + ((u >> 16) & 1u)) >> 16;   // RNE (no NaN inputs here)
    return (unsigned short)u;
}
__device__ __forceinline__ float bf2f(unsigned short h) {
    return __uint_as_float(((unsigned int)h) << 16);
}
__device__ __forceinline__ void gload_lds16(const void* g, void* l) {
    __builtin_amdgcn_global_load_lds(
        (const __attribute__((address_space(1))) void*)g,
        (__attribute__((address_space(3))) void*)l, 16, 0, 0);
}

// ws layout:
//  floats [0, 8192)  total_exp (zeroed)
//  floats [8192,8320) den  [8320,8448) num  [8448,8450) loss_acc  [8452] ticket
//  halves from (ws+8704 floats):
//    qf [0,2097152)  sf [2097152,4194304)  stf [4194304,4227072)   (fp16, scaled)
//    q_hi @4718592  q_lo @6815744  s_hi @8912896  s_lo @11010048   (bf16, scaled)

// One wave per row: inv-norm; write fp16 scaled row (all tensors) and bf16
// hi/lo split (q,s only — consumed by the precision-sensitive qs2 pos path).
// Scale folded per-row: inv_norm * sqrt((1/TEMP)*log2(e)) so that
// exp(sim/TEMP) == exp2(dot of scaled rows).
__global__ __launch_bounds__(256) void normsplit_kernel(
    const float* __restrict__ qm, const float* __restrict__ sm,
    const float* __restrict__ st, float* __restrict__ zero_region,
    _Float16* __restrict__ qf, _Float16* __restrict__ sf, _Float16* __restrict__ stf,
    unsigned short* __restrict__ q_hi, unsigned short* __restrict__ q_lo,
    unsigned short* __restrict__ s_hi, unsigned short* __restrict__ s_lo) {
    if (blockIdx.x < 34) {
        int i = blockIdx.x * 256 + threadIdx.x;
        if (i < 8456) zero_region[i] = 0.0f;
    }
    int row = blockIdx.x * 4 + (threadIdx.x >> 6);
    int lane = threadIdx.x & 63;
    const float* src;
    _Float16* fdst;
    unsigned short *hi = nullptr, *lo = nullptr;
    int r;
    if (row < NQ) {
        r = row; src = qm + (size_t)r * D_DIM; fdst = qf + (size_t)r * D_DIM;
        hi = q_hi + (size_t)r * D_DIM; lo = q_lo + (size_t)r * D_DIM;
    } else if (row < NQ + NS) {
        r = row - NQ; src = sm + (size_t)r * D_DIM; fdst = sf + (size_t)r * D_DIM;
        hi = s_hi + (size_t)r * D_DIM; lo = s_lo + (size_t)r * D_DIM;
    } else if (row < NQ + NS + S_DIM) {
        r = row - NQ - NS; src = st + (size_t)r * D_DIM; fdst = stf + (size_t)r * D_DIM;
    } else return;

    float4 v = reinterpret_cast<const float4*>(src)[lane];
    float ss = v.x * v.x + v.y * v.y + v.z * v.z + v.w * v.w;
    #pragma unroll
    for (int off = 32; off; off >>= 1) ss += __shfl_xor(ss, off);
    float inv = 1.0f / fmaxf(sqrtf(ss), 1e-12f);

    const float CF = sqrtf((1.0f / 0.07f) * 1.44269504088896f);
    float sc = inv * CF;
    float x[4] = {v.x * sc, v.y * sc, v.z * sc, v.w * sc};

    f16x4 fv;
    #pragma unroll
    for (int e = 0; e < 4; e++) fv[e] = (_Float16)x[e];
    reinterpret_cast<f16x4*>(fdst)[lane] = fv;

    if (hi) {
        ushort4 h, l;
        unsigned short* hp = &h.x; unsigned short* lp = &l.x;
        #pragma unroll
        for (int e = 0; e < 4; e++) {
            unsigned short hh = f2bf(x[e]);
            hp[e] = hh;
            lp[e] = f2bf(x[e] - bf2f(hh));
        }
        reinterpret_cast<ushort4*>(hi)[lane] = h;
        reinterpret_cast<ushort4*>(lo)[lane] = l;
    }
}

// fp16 single-pass MFMA GEMM (A*B^T, rows pre-scaled) + exp2 + row-sum.
// BM=BN=128, BK=64, 4 waves (2x2), wave tile 64x64, double-buffered LDS (64KB).
// LDS tile [128 rows][64 halves=128B] is slot-XOR-swizzled (slot ^= row&7,
// slot = 16B unit within the row) -> b128 frag reads are 2-way aliased = free.
// global_load_lds writes LINEAR dest; per-lane global SOURCE applies the same
// involution (rule #21).
// Grid (64, 65): y<64  -> A-pass: total_exp[q-row] += sum exp over s-cols
//                y==64 -> C-pass: den[st-row] += sum exp over q-cols, plus
//                         masked own-section numerator num[st-row].
__global__ __launch_bounds__(256, 2) void mfma_simexp_kernel(
    const _Float16* __restrict__ qf, const _Float16* __restrict__ sf,
    const _Float16* __restrict__ stf,
    float* __restrict__ total_exp, float* __restrict__ den, float* __restrict__ num) {
    __shared__ _Float16 lds[2][2][8192];   // [buf][A,B][128x64] = 64 KB
    const bool cpass = (blockIdx.y == 64);
    const _Float16* A = cpass ? stf : qf;
    const _Float16* B = cpass ? qf : sf;
    float* rowsum = cpass ? den : total_exp;

    const int tid = threadIdx.x;
    const int wid = tid >> 6, lane = tid & 63;
    const int wr = wid >> 1, wc = wid & 1;
    const int row0 = cpass ? 0 : blockIdx.y * 128;
    const int col0 = blockIdx.x * 128;

    f32x4 acc[4][4];
    #pragma unroll
    for (int m = 0; m < 4; m++)
        #pragma unroll
        for (int n = 0; n < 4; n++) acc[m][n] = (f32x4){0.f, 0.f, 0.f, 0.f};

    // Stage A,B tiles for k-chunk kc (halves) into lds[buf]: linear LDS dest,
    // involution-decoded per-lane global source.
    auto STAGE = [&](int buf, int kc) {
        #pragma unroll
        for (int i = 0; i < 4; i++) {
            const int doff = wid * 4096 + i * 1024;       // wave-uniform dest byte
            const int o = doff + lane * 16;               // this lane's dest byte
            const int r = o >> 7;                          // tile row
            const int t = (o >> 4) & 7;                    // 16B slot in row
            const int colh = ((t ^ (r & 7)) << 3);         // halves offset in row
            const size_t ga = ((size_t)(row0 + r) << 8) + kc + colh;
            const size_t gb = ((size_t)(col0 + r) << 8) + kc + colh;
            gload_lds16(A + ga, (char*)&lds[buf][0][0] + doff);
            gload_lds16(B + gb, (char*)&lds[buf][1][0] + doff);
        }
    };
    // swizzled read byte-offset for element row R, k-subchunk ksub (this lane)
    const int kg = lane >> 4;
    auto OFF = [&](int R, int ksub) {
        int s = ksub * 4 + kg;
        return R * 128 + ((s ^ (R & 7)) << 4);
    };

    STAGE(0, 0);
    __syncthreads();
    int cur = 0;
    for (int t = 0; t < 4; t++) {
        if (t < 3) STAGE(cur ^ 1, (t + 1) * 64);
        const char* Ab = (const char*)&lds[cur][0][0];
        const char* Bb = (const char*)&lds[cur][1][0];
        #pragma unroll
        for (int ksub = 0; ksub < 2; ksub++) {
            f16x8 a[4], b[4];
            #pragma unroll
            for (int m = 0; m < 4; m++)
                a[m] = *reinterpret_cast<const f16x8*>(
                    Ab + OFF(wr * 64 + m * 16 + (lane & 15), ksub));
            #pragma unroll
            for (int n = 0; n < 4; n++)
                b[n] = *reinterpret_cast<const f16x8*>(
                    Bb + OFF(wc * 64 + n * 16 + (lane & 15), ksub));
            #pragma unroll
            for (int m = 0; m < 4; m++)
                #pragma unroll
                for (int n = 0; n < 4; n++)
                    acc[m][n] = __builtin_amdgcn_mfma_f32_16x16x32_f16(
                        a[m], b[n], acc[m][n], 0, 0, 0);
        }
        __syncthreads();   // drains prefetch (vmcnt 0) + guards buf reuse
        cur ^= 1;
    }

    // Epilogue: e = exp2(acc); row-sum over this block's 128 cols; atomic add.
    // C/D layout (16x16): col = lane&15, row = (lane>>4)*4 + reg.
    #pragma unroll
    for (int m = 0; m < 4; m++) {
        #pragma unroll
        for (int j = 0; j < 4; j++) {
            const int grow = row0 + wr * 64 + m * 16 + (lane >> 4) * 4 + j;
            float rs = 0.0f, nm = 0.0f;
            #pragma unroll
            for (int n = 0; n < 4; n++) {
                float e = exp2f(acc[m][n][j]);
                rs += e;
                if (cpass) {
                    int col = col0 + wc * 64 + n * 16 + (lane & 15);
                    if ((col >> 6) == grow) nm += e;
                }
            }
            #pragma unroll
            for (int off = 1; off < 16; off <<= 1) {
                rs += __shfl_xor(rs, off);
                if (cpass) nm += __shfl_xor(nm, off);
            }
            if ((lane & 15) == 0) {
                atomicAdd(&rowsum[grow], rs);
                if (cpass) atomicAdd(&num[grow], nm);
            }
        }
    }
}

// qs_loss + finalize. 256 blocks x 128 threads; block = half a section.
// pos/own_exp recomputed in bf16x3 (precision-sensitive path), straight from L2.
// Last block (ticket) finalizes.
__global__ __launch_bounds__(128) void qs2_kernel(
    const unsigned short* __restrict__ q_hi, const unsigned short* __restrict__ q_lo,
    const unsigned short* __restrict__ s_hi, const unsigned short* __restrict__ s_lo,
    const float* __restrict__ total_exp, const float* __restrict__ den,
    const float* __restrict__ num, double* __restrict__ loss_acc,
    unsigned int* __restrict__ ticket, float* __restrict__ out) {
    const int s = blockIdx.x >> 1;
    const int tid = threadIdx.x;
    const int wid2 = ((blockIdx.x & 1) << 1) + (tid >> 6);   // 0..3 within section
    const int lane = tid & 63;
    __shared__ double wsum[2];
    __shared__ float w2[2];
    __shared__ unsigned int winner_s;

    f32x4 acc[4];
    #pragma unroll
    for (int n = 0; n < 4; n++) acc[n] = (f32x4){0.f, 0.f, 0.f, 0.f};

    const int arow = s * 64 + wid2 * 16 + (lane & 15);
    const int koff = (lane >> 4) * 8;
    for (int kc = 0; kc < D_DIM; kc += 32) {
        bf16x8 ah = *reinterpret_cast<const bf16x8*>(&q_hi[(size_t)arow * D_DIM + kc + koff]);
        bf16x8 al = *reinterpret_cast<const bf16x8*>(&q_lo[(size_t)arow * D_DIM + kc + koff]);
        #pragma unroll
        for (int n = 0; n < 4; n++) {
            const int brow = s * 64 + n * 16 + (lane & 15);
            bf16x8 bh = *reinterpret_cast<const bf16x8*>(&s_hi[(size_t)brow * D_DIM + kc + koff]);
            bf16x8 bl = *reinterpret_cast<const bf16x8*>(&s_lo[(size_t)brow * D_DIM + kc + koff]);
            acc[n] = __builtin_amdgcn_mfma_f32_16x16x32_bf16(ah, bh, acc[n], 0, 0, 0);
            acc[n] = __builtin_amdgcn_mfma_f32_16x16x32_bf16(ah, bl, acc[n], 0, 0, 0);
            acc[n] = __builtin_amdgcn_mfma_f32_16x16x32_bf16(al, bh, acc[n], 0, 0, 0);
        }
    }

    const float term2 = expf(-1.0f / 0.07f) * (float)(NS - 1);
    double lacc = 0.0;
    #pragma unroll
    for (int j = 0; j < 4; j++) {
        float e[4];
        float part = 0.0f;
        #pragma unroll
        for (int n = 0; n < 4; n++) { e[n] = exp2f(acc[n][j]); part += e[n]; }
        #pragma unroll
        for (int off = 1; off < 16; off <<= 1) part += __shfl_xor(part, off);
        const int trow = s * 64 + wid2 * 16 + (lane >> 4) * 4 + j;
        const float neg = total_exp[trow] - part;
        #pragma unroll
        for (int n = 0; n < 4; n++) {
            float posv = e[n];
            float t1 = fmaf(-0.1f, posv, neg / 0.9f);
            float Ng = fmaxf(fmaxf(t1, term2), 1e-8f);
            lacc += (double)(-logf(posv / (posv + Ng)));
        }
    }
    #pragma unroll
    for (int off = 1; off < 64; off <<= 1) lacc += __shfl_xor(lacc, off);
    if (lane == 0) wsum[tid >> 6] = lacc;
    __syncthreads();
    if (tid == 0) {
        atomicAdd(loss_acc, wsum[0] + wsum[1]);
        __threadfence();
        winner_s = atomicAdd(ticket, 1u);
    }
    __syncthreads();
    if (winner_s == 255) {
        __threadfence();   // acquire: all other blocks' loss atomics visible
        float l = -logf(num[tid] / den[tid]);   // tid = 0..127 = section
        #pragma unroll
        for (int off = 1; off < 64; off <<= 1) l += __shfl_xor(l, off);
        if ((tid & 63) == 0) w2[tid >> 6] = l;
        __syncthreads();
        if (tid == 0) out[0] = (float)(loss_acc[0] + (double)(w2[0] + w2[1]));
        // at_loss = -log(x/x) = 0 exactly; omitted.
    }
}

extern "C" void kernel_launch(void* const* d_in, const int* in_sizes, int n_in,
                              void* d_out, int out_size, void* d_ws, size_t ws_size,
                              hipStream_t stream) {
    const float* st = (const float*)d_in[1];   // [128,256]
    const float* qm = (const float*)d_in[2];   // [128,64,256]
    const float* sm = (const float*)d_in[3];   // [128,64,256]

    float* ws        = (float*)d_ws;
    float* total_exp = ws;
    float* den       = ws + 8192;
    float* num       = ws + 8320;
    double* loss_acc = (double*)(ws + 8448);
    unsigned int* ticket = (unsigned int*)(ws + 8452);
    _Float16* fbase = (_Float16*)(ws + 8704);
    _Float16* qf  = fbase;
    _Float16* sf  = fbase + 2097152;
    _Float16* stf = fbase + 4194304;
    unsigned short* b16 = (unsigned short*)fbase;
    unsigned short* q_hi = b16 + 4718592;
    unsigned short* q_lo = b16 + 6815744;
    unsigned short* s_hi = b16 + 8912896;
    unsigned short* s_lo = b16 + 11010048;
    float* out = (float*)d_out;

    // 1: zero accumulators + norm + fp16/bf16-split writes
    hipLaunchKernelGGL(normsplit_kernel, dim3(4224), dim3(256), 0, stream,
                       qm, sm, st, ws, qf, sf, stf, q_hi, q_lo, s_hi, s_lo);
    // 2: phase A (y<64): total_exp; phase C (y==64): den/num — fp16 single-pass
    hipLaunchKernelGGL(mfma_simexp_kernel, dim3(64, 65), dim3(256), 0, stream,
                       qf, sf, stf, total_exp, den, num);
    // 3: qs_loss (bf16x3 pos path) + finalize (ticketed last block)
    hipLaunchKernelGGL(qs2_kernel, dim3(256), dim3(128), 0, stream,
                       q_hi, q_lo, s_hi, s_lo, total_exp, den, num,
                       loss_acc, ticket, out);
}

// Round 6
// 197.610 us; speedup vs baseline: 3.1357x; 1.0489x over previous
//
#include <hip/hip_runtime.h>
#include <math.h>

// Problem constants
#define S_DIM 128
#define Q_DIM 64
#define P_DIM 64
#define D_DIM 256
#define NQ (S_DIM * Q_DIM)   // 8192 question rows
#define NS (S_DIM * P_DIM)   // 8192 sentence rows

typedef __attribute__((ext_vector_type(4))) float f32x4;
typedef __attribute__((ext_vector_type(8))) short bf16x8;
typedef __attribute__((ext_vector_type(8))) _Float16 f16x8;
typedef __attribute__((ext_vector_type(4))) _Float16 f16x4;

// ---------- helpers ----------
__device__ __forceinline__ unsigned short f2bf(float f) {
    unsigned int u = __float_as_uint(f);
    u = (u + 0x7fffu + ((u >> 16) & 1u)) >> 16;   // RNE (no NaN inputs here)
    return (unsigned short)u;
}
__device__ __forceinline__ float bf2f(unsigned short h) {
    return __uint_as_float(((unsigned int)h) << 16);
}
__device__ __forceinline__ void gload_lds16(const void* g, void* l) {
    __builtin_amdgcn_global_load_lds(
        (const __attribute__((address_space(1))) void*)g,
        (__attribute__((address_space(3))) void*)l, 16, 0, 0);
}

// ws layout:
//  floats [0, 8192)  total_exp (zeroed)
//  floats [8192,8320) den  [8320,8448) num  [8448,8450) loss_acc  [8452] ticket
//  halves from (ws+8704 floats):
//    qf [0,2097152)  sf [2097152,4194304)  stf [4194304,4227072)   (fp16, scaled)
//    q_hi @4718592  q_lo @6815744  s_hi @8912896  s_lo @11010048   (bf16, scaled)

// One wave per row: inv-norm; write fp16 scaled row (all tensors) and bf16
// hi/lo split (q,s only — consumed by the precision-sensitive qs2 pos path).
// Scale folded per-row: inv_norm * sqrt((1/TEMP)*log2(e)) so that
// exp(sim/TEMP) == exp2(dot of scaled rows).
__global__ __launch_bounds__(256) void normsplit_kernel(
    const float* __restrict__ qm, const float* __restrict__ sm,
    const float* __restrict__ st, float* __restrict__ zero_region,
    _Float16* __restrict__ qf, _Float16* __restrict__ sf, _Float16* __restrict__ stf,
    unsigned short* __restrict__ q_hi, unsigned short* __restrict__ q_lo,
    unsigned short* __restrict__ s_hi, unsigned short* __restrict__ s_lo) {
    if (blockIdx.x < 34) {
        int i = blockIdx.x * 256 + threadIdx.x;
        if (i < 8456) zero_region[i] = 0.0f;
    }
    int row = blockIdx.x * 4 + (threadIdx.x >> 6);
    int lane = threadIdx.x & 63;
    const float* src;
    _Float16* fdst;
    unsigned short *hi = nullptr, *lo = nullptr;
    int r;
    if (row < NQ) {
        r = row; src = qm + (size_t)r * D_DIM; fdst = qf + (size_t)r * D_DIM;
        hi = q_hi + (size_t)r * D_DIM; lo = q_lo + (size_t)r * D_DIM;
    } else if (row < NQ + NS) {
        r = row - NQ; src = sm + (size_t)r * D_DIM; fdst = sf + (size_t)r * D_DIM;
        hi = s_hi + (size_t)r * D_DIM; lo = s_lo + (size_t)r * D_DIM;
    } else if (row < NQ + NS + S_DIM) {
        r = row - NQ - NS; src = st + (size_t)r * D_DIM; fdst = stf + (size_t)r * D_DIM;
    } else return;

    float4 v = reinterpret_cast<const float4*>(src)[lane];
    float ss = v.x * v.x + v.y * v.y + v.z * v.z + v.w * v.w;
    #pragma unroll
    for (int off = 32; off; off >>= 1) ss += __shfl_xor(ss, off);
    float inv = 1.0f / fmaxf(sqrtf(ss), 1e-12f);

    const float CF = sqrtf((1.0f / 0.07f) * 1.44269504088896f);
    float sc = inv * CF;
    float x[4] = {v.x * sc, v.y * sc, v.z * sc, v.w * sc};

    f16x4 fv;
    #pragma unroll
    for (int e = 0; e < 4; e++) fv[e] = (_Float16)x[e];
    reinterpret_cast<f16x4*>(fdst)[lane] = fv;

    if (hi) {
        ushort4 h, l;
        unsigned short* hp = &h.x; unsigned short* lp = &l.x;
        #pragma unroll
        for (int e = 0; e < 4; e++) {
            unsigned short hh = f2bf(x[e]);
            hp[e] = hh;
            lp[e] = f2bf(x[e] - bf2f(hh));
        }
        reinterpret_cast<ushort4*>(hi)[lane] = h;
        reinterpret_cast<ushort4*>(lo)[lane] = l;
    }
}

// fp16 single-pass MFMA GEMM (A*B^T, rows pre-scaled) + exp2 + row-sum.
// BM=BN=128, BK=32, 4 waves (2x2), wave tile 64x64, double-buffered LDS (32KB)
// -> 4 blocks/CU (16 waves) for latency hiding.
// LDS tile layout is k-group subtiled: byte L = kg*2048 + row*16 + h*2
// (kg = k>>3, h = k&7). Frag reads are 16B-contiguous per lane and each
// 8 consecutive lanes span all 32 banks once -> conflict-free. Staging via
// global_load_lds (linear dest) decodes the inverse mapping on the global
// SOURCE address (rule #21).
// Grid (64, 65): y<64  -> A-pass: total_exp[q-row] += sum exp over s-cols
//                y==64 -> C-pass: den[st-row] += sum exp over q-cols, plus
//                         masked own-section numerator num[st-row].
__global__ __launch_bounds__(256, 4) void mfma_simexp_kernel(
    const _Float16* __restrict__ qf, const _Float16* __restrict__ sf,
    const _Float16* __restrict__ stf,
    float* __restrict__ total_exp, float* __restrict__ den, float* __restrict__ num) {
    __shared__ _Float16 lds[2][2][4096];   // [buf][A,B][kg][row][8] = 32 KB
    const bool cpass = (blockIdx.y == 64);
    const _Float16* A = cpass ? stf : qf;
    const _Float16* B = cpass ? qf : sf;
    float* rowsum = cpass ? den : total_exp;

    const int tid = threadIdx.x;
    const int wid = tid >> 6, lane = tid & 63;
    const int wr = wid >> 1, wc = wid & 1;
    const int row0 = cpass ? 0 : blockIdx.y * 128;
    const int col0 = blockIdx.x * 128;

    f32x4 acc[4][4];
    #pragma unroll
    for (int m = 0; m < 4; m++)
        #pragma unroll
        for (int n = 0; n < 4; n++) acc[m][n] = (f32x4){0.f, 0.f, 0.f, 0.f};

    // Stage A,B tiles for k-chunk kc: linear LDS dest byte o decodes to
    // kg = o>>11, row = (o>>4)&127 -> source element (row0+row)*256 + kc + kg*8.
    auto STAGE = [&](int buf, int kc) {
        #pragma unroll
        for (int i = 0; i < 2; i++) {
            const int doff = wid * 2048 + i * 1024;       // wave-uniform dest byte
            const int o = doff + lane * 16;               // this lane's dest byte
            const int kgs = o >> 11;
            const int r = (o >> 4) & 127;
            const size_t ga = ((size_t)(row0 + r) << 8) + kc + kgs * 8;
            const size_t gb = ((size_t)(col0 + r) << 8) + kc + kgs * 8;
            gload_lds16(A + ga, (char*)&lds[buf][0][0] + doff);
            gload_lds16(B + gb, (char*)&lds[buf][1][0] + doff);
        }
    };
    // read byte-offset for tile row R, this lane's k-group (lane>>4)
    const int kg = lane >> 4;
    auto OFF = [&](int R) { return kg * 2048 + R * 16; };

    STAGE(0, 0);
    __syncthreads();
    int cur = 0;
    for (int t = 0; t < 8; t++) {
        if (t < 7) STAGE(cur ^ 1, (t + 1) * 32);
        const char* Ab = (const char*)&lds[cur][0][0];
        const char* Bb = (const char*)&lds[cur][1][0];
        f16x8 a[4], b[4];
        #pragma unroll
        for (int m = 0; m < 4; m++)
            a[m] = *reinterpret_cast<const f16x8*>(Ab + OFF(wr * 64 + m * 16 + (lane & 15)));
        #pragma unroll
        for (int n = 0; n < 4; n++)
            b[n] = *reinterpret_cast<const f16x8*>(Bb + OFF(wc * 64 + n * 16 + (lane & 15)));
        #pragma unroll
        for (int m = 0; m < 4; m++)
            #pragma unroll
            for (int n = 0; n < 4; n++)
                acc[m][n] = __builtin_amdgcn_mfma_f32_16x16x32_f16(
                    a[m], b[n], acc[m][n], 0, 0, 0);
        __syncthreads();   // drains prefetch (vmcnt 0) + guards buf reuse
        cur ^= 1;
    }

    // Epilogue: e = exp2(acc); row-sum over this block's 128 cols; atomic add.
    // C/D layout (16x16): col = lane&15, row = (lane>>4)*4 + reg.
    #pragma unroll
    for (int m = 0; m < 4; m++) {
        #pragma unroll
        for (int j = 0; j < 4; j++) {
            const int grow = row0 + wr * 64 + m * 16 + (lane >> 4) * 4 + j;
            float rs = 0.0f, nm = 0.0f;
            #pragma unroll
            for (int n = 0; n < 4; n++) {
                float e = exp2f(acc[m][n][j]);
                rs += e;
                if (cpass) {
                    int col = col0 + wc * 64 + n * 16 + (lane & 15);
                    if ((col >> 6) == grow) nm += e;
                }
            }
            #pragma unroll
            for (int off = 1; off < 16; off <<= 1) {
                rs += __shfl_xor(rs, off);
                if (cpass) nm += __shfl_xor(nm, off);
            }
            if ((lane & 15) == 0) {
                atomicAdd(&rowsum[grow], rs);
                if (cpass) atomicAdd(&num[grow], nm);
            }
        }
    }
}

// qs_loss + finalize. 256 blocks x 128 threads; block = half a section.
// pos/own_exp recomputed in bf16x3 (precision-sensitive path), straight from
// L2; all 16 A-frags preloaded so the 16 B-loads per n are independent (ILP).
// Last block (ticket) finalizes.
__global__ __launch_bounds__(128) void qs2_kernel(
    const unsigned short* __restrict__ q_hi, const unsigned short* __restrict__ q_lo,
    const unsigned short* __restrict__ s_hi, const unsigned short* __restrict__ s_lo,
    const float* __restrict__ total_exp, const float* __restrict__ den,
    const float* __restrict__ num, double* __restrict__ loss_acc,
    unsigned int* __restrict__ ticket, float* __restrict__ out) {
    const int s = blockIdx.x >> 1;
    const int tid = threadIdx.x;
    const int wid2 = ((blockIdx.x & 1) << 1) + (tid >> 6);   // 0..3 within section
    const int lane = tid & 63;
    __shared__ double wsum[2];
    __shared__ float w2[2];
    __shared__ unsigned int winner_s;

    const int arow = s * 64 + wid2 * 16 + (lane & 15);
    const int koff = (lane >> 4) * 8;

    bf16x8 ah[8], al[8];
    #pragma unroll
    for (int k8 = 0; k8 < 8; k8++) {
        ah[k8] = *reinterpret_cast<const bf16x8*>(&q_hi[(size_t)arow * D_DIM + k8 * 32 + koff]);
        al[k8] = *reinterpret_cast<const bf16x8*>(&q_lo[(size_t)arow * D_DIM + k8 * 32 + koff]);
    }

    f32x4 acc[4];
    #pragma unroll
    for (int n = 0; n < 4; n++) acc[n] = (f32x4){0.f, 0.f, 0.f, 0.f};
    #pragma unroll
    for (int n = 0; n < 4; n++) {
        const int brow = s * 64 + n * 16 + (lane & 15);
        #pragma unroll
        for (int k8 = 0; k8 < 8; k8++) {
            bf16x8 bh = *reinterpret_cast<const bf16x8*>(&s_hi[(size_t)brow * D_DIM + k8 * 32 + koff]);
            bf16x8 bl = *reinterpret_cast<const bf16x8*>(&s_lo[(size_t)brow * D_DIM + k8 * 32 + koff]);
            acc[n] = __builtin_amdgcn_mfma_f32_16x16x32_bf16(ah[k8], bh, acc[n], 0, 0, 0);
            acc[n] = __builtin_amdgcn_mfma_f32_16x16x32_bf16(ah[k8], bl, acc[n], 0, 0, 0);
            acc[n] = __builtin_amdgcn_mfma_f32_16x16x32_bf16(al[k8], bh, acc[n], 0, 0, 0);
        }
    }

    const float term2 = expf(-1.0f / 0.07f) * (float)(NS - 1);
    double lacc = 0.0;
    #pragma unroll
    for (int j = 0; j < 4; j++) {
        float e[4];
        float part = 0.0f;
        #pragma unroll
        for (int n = 0; n < 4; n++) { e[n] = exp2f(acc[n][j]); part += e[n]; }
        #pragma unroll
        for (int off = 1; off < 16; off <<= 1) part += __shfl_xor(part, off);
        const int trow = s * 64 + wid2 * 16 + (lane >> 4) * 4 + j;
        const float neg = total_exp[trow] - part;
        #pragma unroll
        for (int n = 0; n < 4; n++) {
            float posv = e[n];
            float t1 = fmaf(-0.1f, posv, neg / 0.9f);
            float Ng = fmaxf(fmaxf(t1, term2), 1e-8f);
            lacc += (double)(-logf(posv / (posv + Ng)));
        }
    }
    #pragma unroll
    for (int off = 1; off < 64; off <<= 1) lacc += __shfl_xor(lacc, off);
    if (lane == 0) wsum[tid >> 6] = lacc;
    __syncthreads();
    if (tid == 0) {
        atomicAdd(loss_acc, wsum[0] + wsum[1]);
        __threadfence();
        winner_s = atomicAdd(ticket, 1u);
    }
    __syncthreads();
    if (winner_s == 255) {
        __threadfence();   // acquire: all other blocks' loss atomics visible
        float l = -logf(num[tid] / den[tid]);   // tid = 0..127 = section
        #pragma unroll
        for (int off = 1; off < 64; off <<= 1) l += __shfl_xor(l, off);
        if ((tid & 63) == 0) w2[tid >> 6] = l;
        __syncthreads();
        if (tid == 0) out[0] = (float)(loss_acc[0] + (double)(w2[0] + w2[1]));
        // at_loss = -log(x/x) = 0 exactly; omitted.
    }
}

extern "C" void kernel_launch(void* const* d_in, const int* in_sizes, int n_in,
                              void* d_out, int out_size, void* d_ws, size_t ws_size,
                              hipStream_t stream) {
    const float* st = (const float*)d_in[1];   // [128,256]
    const float* qm = (const float*)d_in[2];   // [128,64,256]
    const float* sm = (const float*)d_in[3];   // [128,64,256]

    float* ws        = (float*)d_ws;
    float* total_exp = ws;
    float* den       = ws + 8192;
    float* num       = ws + 8320;
    double* loss_acc = (double*)(ws + 8448);
    unsigned int* ticket = (unsigned int*)(ws + 8452);
    _Float16* fbase = (_Float16*)(ws + 8704);
    _Float16* qf  = fbase;
    _Float16* sf  = fbase + 2097152;
    _Float16* stf = fbase + 4194304;
    unsigned short* b16 = (unsigned short*)fbase;
    unsigned short* q_hi = b16 + 4718592;
    unsigned short* q_lo = b16 + 6815744;
    unsigned short* s_hi = b16 + 8912896;
    unsigned short* s_lo = b16 + 11010048;
    float* out = (float*)d_out;

    // 1: zero accumulators + norm + fp16/bf16-split writes
    hipLaunchKernelGGL(normsplit_kernel, dim3(4224), dim3(256), 0, stream,
                       qm, sm, st, ws, qf, sf, stf, q_hi, q_lo, s_hi, s_lo);
    // 2: phase A (y<64): total_exp; phase C (y==64): den/num — fp16 single-pass
    hipLaunchKernelGGL(mfma_simexp_kernel, dim3(64, 65), dim3(256), 0, stream,
                       qf, sf, stf, total_exp, den, num);
    // 3: qs_loss (bf16x3 pos path) + finalize (ticketed last block)
    hipLaunchKernelGGL(qs2_kernel, dim3(256), dim3(128), 0, stream,
                       q_hi, q_lo, s_hi, s_lo, total_exp, den, num,
                       loss_acc, ticket, out);
}